// Round 6
// baseline (449.153 us; speedup 1.0000x reference)
//
#include <hip/hip_runtime.h>
#include <hip/hip_bf16.h>

typedef unsigned short u16;
typedef __attribute__((ext_vector_type(8))) short bf16x8;
typedef __attribute__((ext_vector_type(4))) float f32x4;

#define MFMA16(a, b, c) __builtin_amdgcn_mfma_f32_16x16x32_bf16(a, b, c, 0, 0, 0)

__device__ __forceinline__ u16 f2b(float f) {
  union { float f; unsigned u; } x; x.f = f;
  return (u16)((x.u + 0x7fffu + ((x.u >> 16) & 1u)) >> 16);
}

__device__ __forceinline__ void gload_lds16(const void* g, void* l) {
  __builtin_amdgcn_global_load_lds(
      (const __attribute__((address_space(1))) void*)g,
      (__attribute__((address_space(3))) void*)l, 16, 0, 0);
}

// stage 64 rows x 192 cols bf16, chunk(8xbf16) XOR-swizzled by row&7.
// LDS dest linear (wave-uniform base + lane*16), global source pre-swizzled.
__device__ __forceinline__ void stage_64x192(const u16* __restrict__ src,
                                             int stride, u16* dst, int wave,
                                             int lane) {
#pragma unroll
  for (int it = 0; it < 6; ++it) {
    int id = (it * 4 + wave) * 64 + lane;
    int row = id / 24, ph = id - row * 24;
    int lch = (ph & 24) | ((ph ^ (row & 7)) & 7);
    gload_lds16(src + (size_t)row * stride + lch * 8,
                dst + (it * 4 + wave) * 512);
  }
}

// stage 192 rows x 64 cols bf16 (8 chunks/row), same swizzle discipline.
__device__ __forceinline__ void stage_192x64(const u16* __restrict__ src,
                                             int stride, u16* dst, int wave,
                                             int lane) {
#pragma unroll
  for (int it = 0; it < 6; ++it) {
    int id = (it * 4 + wave) * 64 + lane;
    int row = id >> 3, ph = id & 7;
    int lch = ph ^ (row & 7);
    gload_lds16(src + (size_t)row * stride + lch * 8,
                dst + (it * 4 + wave) * 512);
  }
}

// ---------------- weight f32 -> bf16 ----------------
__global__ __launch_bounds__(256) void cvt_kernel(const float* __restrict__ s,
                                                  u16* __restrict__ d, int n) {
  int i = blockIdx.x * 256 + threadIdx.x;
  if (i < n) d[i] = f2b(s[i]);
}

// ---------------- fused LN1 + shift/window + QKV GEMM ----------------
__global__ __launch_bounds__(256, 2) void qkv_fused(
    const float* __restrict__ x, const float* __restrict__ n1w,
    const float* __restrict__ n1b, const u16* __restrict__ qkvw,
    const float* __restrict__ qkvb_, u16* __restrict__ qb,
    u16* __restrict__ kb, u16* __restrict__ vb, int tok0) {
  __shared__ __align__(16) u16 lds[36864];
  u16* sA = lds;
  u16* sB0 = lds + 12288;
  u16* sB1 = lds + 24576;
  int tid = threadIdx.x, wave = tid >> 6, lane = tid & 63;
  int g = lane >> 4, c = lane & 15, wr = wave * 16;
  int m0 = blockIdx.x * 64;
  // prefetch B chunk 0 while doing LN
  stage_64x192(qkvw, 192, sB0, wave, lane);
  // LN1 over shifted-window source rows (C-layout in regs)
  float vals[12][4];
  int srcrow[4];
#pragma unroll
  for (int reg = 0; reg < 4; ++reg) {
    int rg = tok0 + m0 + wr + 4 * g + reg;
    int win = rg / 49, n = rg - win * 49;
    int bb = win >> 6, wi = win & 63, wh = wi >> 3, ww = wi & 7;
    int rr = n / 7, cc = n - rr * 7;
    int hs = wh * 7 + rr + 3; if (hs >= 56) hs -= 56;
    int ws = ww * 7 + cc + 3; if (ws >= 56) ws -= 56;
    srcrow[reg] = bb * 3136 + hs * 56 + ws;
  }
#pragma unroll
  for (int nt = 0; nt < 12; ++nt)
#pragma unroll
    for (int reg = 0; reg < 4; ++reg)
      vals[nt][reg] = x[(size_t)srcrow[reg] * 192 + nt * 16 + c];
#pragma unroll
  for (int reg = 0; reg < 4; ++reg) {
    float s = 0.f;
#pragma unroll
    for (int nt = 0; nt < 12; ++nt) s += vals[nt][reg];
    s += __shfl_xor(s, 1, 64); s += __shfl_xor(s, 2, 64);
    s += __shfl_xor(s, 4, 64); s += __shfl_xor(s, 8, 64);
    float m = s * (1.f / 192.f), q = 0.f;
#pragma unroll
    for (int nt = 0; nt < 12; ++nt) { float d = vals[nt][reg] - m; q += d * d; }
    q += __shfl_xor(q, 1, 64); q += __shfl_xor(q, 2, 64);
    q += __shfl_xor(q, 4, 64); q += __shfl_xor(q, 8, 64);
    float rs = rsqrtf(q * (1.f / 192.f) + 1e-5f);
#pragma unroll
    for (int nt = 0; nt < 12; ++nt) vals[nt][reg] = (vals[nt][reg] - m) * rs;
  }
#pragma unroll
  for (int nt = 0; nt < 12; ++nt) {
    float wv = n1w[nt * 16 + c], bv = n1b[nt * 16 + c];
#pragma unroll
    for (int reg = 0; reg < 4; ++reg) {
      int r = wr + 4 * g + reg;
      int ch = nt * 2 + (c >> 3);
      int ph = (ch & 24) | ((ch ^ (r & 7)) & 7);
      sA[r * 192 + ph * 8 + (c & 7)] = f2b(vals[nt][reg] * wv + bv);
    }
  }
  __syncthreads();
  bf16x8 afr[6];
  {
    int ar = wr + c;
#pragma unroll
    for (int ks = 0; ks < 6; ++ks) {
      int ch = ks * 4 + g;
      int ph = (ch & 24) | ((ch ^ (ar & 7)) & 7);
      afr[ks] = *(const bf16x8*)(sA + ar * 192 + ph * 8);
    }
  }
  int win0 = tok0 / 49;
  for (int j = 0; j < 9; ++j) {
    u16* nb = (j & 1) ? sB0 : sB1;
    if (j < 8) {
      stage_64x192(qkvw + (size_t)(j + 1) * 64 * 192, 192, nb, wave, lane);
      asm volatile("s_waitcnt vmcnt(6)" ::: "memory");
    } else {
      asm volatile("s_waitcnt vmcnt(0)" ::: "memory");
    }
    __syncthreads();
    const u16* sb = (j & 1) ? sB1 : sB0;
    f32x4 S[4] = {{0,0,0,0},{0,0,0,0},{0,0,0,0},{0,0,0,0}};
#pragma unroll
    for (int ks = 0; ks < 6; ++ks)
#pragma unroll
      for (int nt = 0; nt < 4; ++nt) {
        int br = nt * 16 + c;
        int ch = ks * 4 + g;
        int ph = (ch & 24) | ((ch ^ (br & 7)) & 7);
        bf16x8 bf = *(const bf16x8*)(sb + br * 192 + ph * 8);
        S[nt] = MFMA16(afr[ks], bf, S[nt]);
      }
    int which = j / 3;  // 0=q 1=k 2=v (uniform per chunk)
    u16* dst = which == 0 ? qb : (which == 1 ? kb : vb);
#pragma unroll
    for (int nt = 0; nt < 4; ++nt) {
      int jc = j * 64 + nt * 16 + c;
      int jj = jc - which * 192;
      int hh = jj >> 5, d = jj & 31;
      float bv = qkvb_[jc];
#pragma unroll
      for (int reg = 0; reg < 4; ++reg) {
        int rg = tok0 + m0 + wr + 4 * g + reg;
        int win = rg / 49, n = rg - win * 49;
        dst[((size_t)((win - win0) * 6 + hh) * 49 + n) * 32 + d] =
            f2b(S[nt][reg] + bv);
      }
    }
    __syncthreads();
  }
}

// ---------------- attention: one (window, head) per block ----------------
__global__ __launch_bounds__(256) void attn_kernel(
    const u16* __restrict__ qb, const u16* __restrict__ kb,
    const u16* __restrict__ vb, const float* __restrict__ rpb,
    const float* __restrict__ amask, u16* __restrict__ aout, int win0) {
  __shared__ __align__(16) u16 qs[64 * 32], ks[64 * 32], vst[32 * 64];
  __shared__ __align__(16) float S[64 * 68];
  __shared__ __align__(16) u16 P[64 * 64];
  int tid = threadIdx.x;
  int blk = blockIdx.x;
  int winl = blk / 6, head = blk - winl * 6;
  int wi = (win0 + winl) & 63;
  const size_t base = (size_t)(winl * 6 + head) * 49 * 32;
  {
    int row = tid >> 2, kcl = tid & 3;
    int phys = kcl ^ (row & 3);
    uint4 qv = make_uint4(0, 0, 0, 0), kv = qv, vv = qv;
    if (row < 49) {
      size_t o = base + (size_t)row * 32 + kcl * 8;
      qv = *(const uint4*)(qb + o);
      kv = *(const uint4*)(kb + o);
      vv = *(const uint4*)(vb + o);
    }
    *(uint4*)(qs + row * 32 + phys * 8) = qv;
    *(uint4*)(ks + row * 32 + phys * 8) = kv;
    alignas(16) u16 vu[8];
    *(uint4*)vu = vv;
    int c8 = kcl * 8;
    int kc = row >> 3;
#pragma unroll
    for (int j = 0; j < 8; ++j) {
      int d = c8 + j;
      vst[d * 64 + ((kc ^ (d & 7)) * 8) + (row & 7)] = vu[j];
    }
  }
  __syncthreads();
  int wave = tid >> 6, lane = tid & 63;
  int col = lane & 15, g = lane >> 4;
  {
    int ar = wave * 16 + col;
    bf16x8 af = *(const bf16x8*)(qs + ar * 32 + ((g ^ (ar & 3)) * 8));
    f32x4 zero = {0.f, 0.f, 0.f, 0.f};
#pragma unroll
    for (int nt = 0; nt < 4; ++nt) {
      int br = nt * 16 + col;
      bf16x8 bfr = *(const bf16x8*)(ks + br * 32 + ((g ^ (br & 3)) * 8));
      f32x4 sacc = MFMA16(af, bfr, zero);
#pragma unroll
      for (int reg = 0; reg < 4; ++reg)
        S[(wave * 16 + 4 * g + reg) * 68 + nt * 16 + col] = sacc[reg];
    }
  }
  __syncthreads();
  {
    int r = tid >> 2, p = tid & 3;
    int rb = (r < 49) ? r : 0;
    int i1 = rb / 7, j1 = rb - i1 * 7;
    const float scale = 0.17677669529663687f;
    const float* Srow = S + r * 68;
    float vals[16];
    float mx = -1e30f;
#pragma unroll
    for (int t = 0; t < 16; ++t) {
      int cc = p * 16 + t;
      float v = -1e30f;
      if (cc < 49) {
        int i2 = cc / 7, j2 = cc - i2 * 7;
        int ridx = (i1 - i2 + 6) * 13 + (j1 - j2 + 6);
        v = Srow[cc] * scale + rpb[ridx * 6 + head] +
            amask[(size_t)wi * 2401 + rb * 49 + cc];
      }
      vals[t] = v;
      mx = fmaxf(mx, v);
    }
    mx = fmaxf(mx, __shfl_xor(mx, 1, 64));
    mx = fmaxf(mx, __shfl_xor(mx, 2, 64));
    float se = 0.f;
#pragma unroll
    for (int t = 0; t < 16; ++t) {
      float e = __expf(vals[t] - mx);
      vals[t] = e;
      se += e;
    }
    se += __shfl_xor(se, 1, 64);
    se += __shfl_xor(se, 2, 64);
    float inv = 1.0f / se;
#pragma unroll
    for (int t = 0; t < 16; ++t) {
      int cc = p * 16 + t;
      P[r * 64 + (((cc >> 3) ^ (r & 7)) * 8) + (cc & 7)] = f2b(vals[t] * inv);
    }
  }
  __syncthreads();
  {
    f32x4 oacc[2] = {{0,0,0,0},{0,0,0,0}};
    int ar = wave * 16 + col;
#pragma unroll
    for (int kt = 0; kt < 2; ++kt) {
      bf16x8 pf = *(const bf16x8*)(P + ar * 64 + (((kt * 4 + g) ^ (ar & 7)) * 8));
#pragma unroll
      for (int nt = 0; nt < 2; ++nt) {
        int d = nt * 16 + col;
        bf16x8 vf = *(const bf16x8*)(vst + d * 64 + (((kt * 4 + g) ^ (d & 7)) * 8));
        oacc[nt] = MFMA16(pf, vf, oacc[nt]);
      }
    }
#pragma unroll
    for (int nt = 0; nt < 2; ++nt)
#pragma unroll
      for (int reg = 0; reg < 4; ++reg) {
        int rloc = wave * 16 + 4 * g + reg;
        if (rloc < 49)
          aout[((size_t)winl * 49 + rloc) * 192 + head * 32 + nt * 16 + col] =
              f2b(oacc[nt][reg]);
      }
  }
}

// ---------------- fused proj GEMM + window reverse + unshift + residual ----------------
__global__ __launch_bounds__(256, 2) void proj_fused(
    const u16* __restrict__ aout, const u16* __restrict__ projw,
    const float* __restrict__ pb, const float* __restrict__ x,
    float* __restrict__ out, int tok0) {
  __shared__ __align__(16) u16 lds[36864];
  u16* sA = lds;
  u16* sB0 = lds + 12288;
  u16* sB1 = lds + 24576;
  int tid = threadIdx.x, wave = tid >> 6, lane = tid & 63;
  int g = lane >> 4, c = lane & 15, wr = wave * 16;
  int m0 = blockIdx.x * 64;
  stage_64x192(aout + (size_t)m0 * 192, 192, sA, wave, lane);
  stage_64x192(projw, 192, sB0, wave, lane);
  asm volatile("s_waitcnt vmcnt(0)" ::: "memory");
  __syncthreads();
  bf16x8 afr[6];
  {
    int ar = wr + c;
#pragma unroll
    for (int ks = 0; ks < 6; ++ks) {
      int ch = ks * 4 + g;
      int ph = (ch & 24) | ((ch ^ (ar & 7)) & 7);
      afr[ks] = *(const bf16x8*)(sA + ar * 192 + ph * 8);
    }
  }
  // row -> output token mapping (window reverse + unshift)
  size_t trow[4];
#pragma unroll
  for (int reg = 0; reg < 4; ++reg) {
    int rg = tok0 + m0 + wr + 4 * g + reg;
    int win = rg / 49, n = rg - win * 49;
    int b_ = win >> 6, wi = win & 63;
    int wh = wi >> 3, ww = wi & 7;
    int rr = n / 7, cc = n - rr * 7;
    int hd_ = wh * 7 + rr + 3; if (hd_ >= 56) hd_ -= 56;
    int wd = ww * 7 + cc + 3; if (wd >= 56) wd -= 56;
    trow[reg] = (size_t)b_ * 3136 + hd_ * 56 + wd;
  }
  for (int j = 0; j < 3; ++j) {
    if (j < 2) {
      u16* nb = (j & 1) ? sB0 : sB1;
      stage_64x192(projw + (size_t)(j + 1) * 64 * 192, 192, nb, wave, lane);
      asm volatile("s_waitcnt vmcnt(6)" ::: "memory");
    } else {
      asm volatile("s_waitcnt vmcnt(0)" ::: "memory");
    }
    __syncthreads();
    const u16* sb = (j & 1) ? sB1 : sB0;
    f32x4 S[4] = {{0,0,0,0},{0,0,0,0},{0,0,0,0},{0,0,0,0}};
#pragma unroll
    for (int ks = 0; ks < 6; ++ks)
#pragma unroll
      for (int nt = 0; nt < 4; ++nt) {
        int br = nt * 16 + c;
        int ch = ks * 4 + g;
        int ph = (ch & 24) | ((ch ^ (br & 7)) & 7);
        bf16x8 bf = *(const bf16x8*)(sb + br * 192 + ph * 8);
        S[nt] = MFMA16(afr[ks], bf, S[nt]);
      }
#pragma unroll
    for (int nt = 0; nt < 4; ++nt) {
      int jc = j * 64 + nt * 16 + c;
      float bv = pb[jc];
#pragma unroll
      for (int reg = 0; reg < 4; ++reg) {
        size_t o = trow[reg] * 192 + jc;
        out[o] = x[o] + S[nt][reg] + bv;
      }
    }
    __syncthreads();
  }
}

// ---------------- fused LN2 + fc1 + GELU + fc2 + residual ----------------
// 256 threads / 4 waves, M=128 (2 row-groups per wave), 64 KB LDS -> 2 blocks/CU.
// Single-buffered weight chunks; fc1(j+1) restaged during PV phase.
__global__ __launch_bounds__(256, 2) void mlp_fused(
    const float* __restrict__ n2w, const float* __restrict__ n2b,
    const u16* __restrict__ w1, const float* __restrict__ b1,
    const u16* __restrict__ w2, const float* __restrict__ b2,
    float* __restrict__ out) {
  __shared__ __align__(16) u16 lds[32768];  // 64 KB
  u16* sA  = lds;          // 128x192 (24576 u16), overlaid by weights after use
  u16* cb1 = lds;          // 64x192 fc1 chunk
  u16* cb2 = lds + 12288;  // 192x64 fc2 chunk
  u16* sP  = lds + 24576;  // 128x64
  int tid = threadIdx.x, wave = tid >> 6, lane = tid & 63;
  int g = lane >> 4, c = lane & 15;
  int m0 = blockIdx.x * 128;
  int wbase = wave * 32;
  // LN2 one row-group at a time (keeps transient VGPR low); write sA bf16
#pragma unroll
  for (int rg = 0; rg < 2; ++rg) {
    float v[12][4];
    int rr[4];
#pragma unroll
    for (int reg = 0; reg < 4; ++reg)
      rr[reg] = m0 + wbase + rg * 16 + 4 * g + reg;
#pragma unroll
    for (int nt = 0; nt < 12; ++nt)
#pragma unroll
      for (int reg = 0; reg < 4; ++reg)
        v[nt][reg] = out[(size_t)rr[reg] * 192 + nt * 16 + c];
#pragma unroll
    for (int reg = 0; reg < 4; ++reg) {
      float s = 0.f;
#pragma unroll
      for (int nt = 0; nt < 12; ++nt) s += v[nt][reg];
      s += __shfl_xor(s, 1, 64); s += __shfl_xor(s, 2, 64);
      s += __shfl_xor(s, 4, 64); s += __shfl_xor(s, 8, 64);
      float m = s * (1.f / 192.f), q = 0.f;
#pragma unroll
      for (int nt = 0; nt < 12; ++nt) { float d = v[nt][reg] - m; q += d * d; }
      q += __shfl_xor(q, 1, 64); q += __shfl_xor(q, 2, 64);
      q += __shfl_xor(q, 4, 64); q += __shfl_xor(q, 8, 64);
      float rs = rsqrtf(q * (1.f / 192.f) + 1e-5f);
#pragma unroll
      for (int nt = 0; nt < 12; ++nt) v[nt][reg] = (v[nt][reg] - m) * rs;
    }
#pragma unroll
    for (int nt = 0; nt < 12; ++nt) {
      float wv = n2w[nt * 16 + c], bv = n2b[nt * 16 + c];
#pragma unroll
      for (int reg = 0; reg < 4; ++reg) {
        int r = wbase + rg * 16 + 4 * g + reg;
        int ch = nt * 2 + (c >> 3);
        int ph = (ch & 24) | ((ch ^ (r & 7)) & 7);
        sA[r * 192 + ph * 8 + (c & 7)] = f2b(v[nt][reg] * wv + bv);
      }
    }
  }
  __syncthreads();  // sA visible
  bf16x8 afr0[6], afr1[6];
  {
    int a0 = wbase + c, a1 = wbase + 16 + c;
#pragma unroll
    for (int ks = 0; ks < 6; ++ks) {
      int ch = ks * 4 + g;
      int p0 = (ch & 24) | ((ch ^ (a0 & 7)) & 7);
      int p1 = (ch & 24) | ((ch ^ (a1 & 7)) & 7);
      afr0[ks] = *(const bf16x8*)(sA + a0 * 192 + p0 * 8);
      afr1[ks] = *(const bf16x8*)(sA + a1 * 192 + p1 * 8);
    }
  }
  __syncthreads();  // all afr reads done (drained) -> sA region reusable
  stage_64x192(w1, 192, cb1, wave, lane);
  stage_192x64(w2, 768, cb2, wave, lane);
  f32x4 o0[12], o1[12];
#pragma unroll
  for (int i = 0; i < 12; ++i) {
    o0[i] = (f32x4){0.f, 0.f, 0.f, 0.f};
    o1[i] = (f32x4){0.f, 0.f, 0.f, 0.f};
  }
  for (int j = 0; j < 12; ++j) {
    __syncthreads();  // staged weights visible (barrier drains vmcnt)
    // ---- fc1: S = A @ w1_chunk^T (each B-frag read feeds 2 MFMAs) ----
    f32x4 S0[4] = {{0,0,0,0},{0,0,0,0},{0,0,0,0},{0,0,0,0}};
    f32x4 S1[4] = {{0,0,0,0},{0,0,0,0},{0,0,0,0},{0,0,0,0}};
#pragma unroll
    for (int ks = 0; ks < 6; ++ks)
#pragma unroll
      for (int nt = 0; nt < 4; ++nt) {
        int br = nt * 16 + c;
        int ch = ks * 4 + g;
        int ph = (ch & 24) | ((ch ^ (br & 7)) & 7);
        bf16x8 bf = *(const bf16x8*)(cb1 + br * 192 + ph * 8);
        S0[nt] = MFMA16(afr0[ks], bf, S0[nt]);
        S1[nt] = MFMA16(afr1[ks], bf, S1[nt]);
      }
    // ---- fast GELU -> sP (both row-groups) ----
#pragma unroll
    for (int nt = 0; nt < 4; ++nt) {
      float bv = b1[j * 64 + nt * 16 + c];
      int col = nt * 16 + c;
#pragma unroll
      for (int reg = 0; reg < 4; ++reg) {
        {
          int r = wbase + 4 * g + reg;
          float vv = S0[nt][reg] + bv;
          float u2 = vv * (1.5957691216f + 0.0713548163f * vv * vv);
          float gl = vv / (1.f + __expf(-u2));
          int ph = (col >> 3) ^ (r & 7);
          sP[r * 64 + ph * 8 + (col & 7)] = f2b(gl);
        }
        {
          int r = wbase + 16 + 4 * g + reg;
          float vv = S1[nt][reg] + bv;
          float u2 = vv * (1.5957691216f + 0.0713548163f * vv * vv);
          float gl = vv / (1.f + __expf(-u2));
          int ph = (col >> 3) ^ (r & 7);
          sP[r * 64 + ph * 8 + (col & 7)] = f2b(gl);
        }
      }
    }
    __syncthreads();  // sP visible; all cb1 reads done
    // restage fc1(j+1) now -> latency overlaps the PV phase
    if (j < 11) stage_64x192(w1 + (size_t)(j + 1) * 64 * 192, 192, cb1, wave, lane);
    // ---- PV: oacc += P @ w2_chunk ----
#pragma unroll
    for (int ks = 0; ks < 2; ++ks) {
      int ch = ks * 4 + g;
      int pr0 = wbase + c, pr1 = wbase + 16 + c;
      bf16x8 pf0 = *(const bf16x8*)(sP + pr0 * 64 + ((ch ^ (pr0 & 7)) * 8));
      bf16x8 pf1 = *(const bf16x8*)(sP + pr1 * 64 + ((ch ^ (pr1 & 7)) * 8));
#pragma unroll
      for (int nt = 0; nt < 12; ++nt) {
        int c2 = nt * 16 + c;
        bf16x8 bf = *(const bf16x8*)(cb2 + c2 * 64 + ((ch ^ (c2 & 7)) * 8));
        o0[nt] = MFMA16(pf0, bf, o0[nt]);
        o1[nt] = MFMA16(pf1, bf, o1[nt]);
      }
    }
    __syncthreads();  // cb2 + sP reads done
    if (j < 11) stage_192x64(w2 + (size_t)(j + 1) * 64, 768, cb2, wave, lane);
  }
  // epilogue: residual (re-read from out) + bias
#pragma unroll
  for (int nt = 0; nt < 12; ++nt) {
    float bv = b2[nt * 16 + c];
#pragma unroll
    for (int reg = 0; reg < 4; ++reg) {
      size_t oo0 = (size_t)(m0 + wbase + 4 * g + reg) * 192 + nt * 16 + c;
      size_t oo1 = (size_t)(m0 + wbase + 16 + 4 * g + reg) * 192 + nt * 16 + c;
      out[oo0] = out[oo0] + o0[nt][reg] + bv;
      out[oo1] = out[oo1] + o1[nt][reg] + bv;
    }
  }
}

extern "C" void kernel_launch(void* const* d_in, const int* in_sizes, int n_in,
                              void* d_out, int out_size, void* d_ws, size_t ws_size,
                              hipStream_t stream) {
  (void)in_sizes; (void)n_in; (void)out_size;
  const float* x     = (const float*)d_in[0];
  const float* amask = (const float*)d_in[1];
  const float* n1w   = (const float*)d_in[2];
  const float* n1b   = (const float*)d_in[3];
  const float* qkvw  = (const float*)d_in[4];
  const float* qkvb  = (const float*)d_in[5];
  const float* rpb   = (const float*)d_in[6];
  const float* projw = (const float*)d_in[7];
  const float* projb = (const float*)d_in[8];
  const float* n2w   = (const float*)d_in[9];
  const float* n2b   = (const float*)d_in[10];
  const float* fc1w  = (const float*)d_in[11];
  const float* fc1b  = (const float*)d_in[12];
  const float* fc2w  = (const float*)d_in[13];
  const float* fc2b  = (const float*)d_in[14];
  float* out = (float*)d_out;
  char* ws = (char*)d_ws;

  u16* qkvw_bf = (u16*)(ws);
  u16* projw_bf = (u16*)(ws + 221184);
  u16* fc1w_bf = (u16*)(ws + 221184 + 73728);
  u16* fc2w_bf = (u16*)(ws + 221184 + 73728 + 294912);
  char* arena = ws + (1 << 20);
  size_t arena_sz = ws_size > (1 << 20) ? ws_size - (1 << 20) : 0;

  cvt_kernel<<<(110592 + 255) / 256, 256, 0, stream>>>(qkvw, qkvw_bf, 110592);
  cvt_kernel<<<(36864 + 255) / 256, 256, 0, stream>>>(projw, projw_bf, 36864);
  cvt_kernel<<<(147456 + 255) / 256, 256, 0, stream>>>(fc1w, fc1w_bf, 147456);
  cvt_kernel<<<(147456 + 255) / 256, 256, 0, stream>>>(fc2w, fc2w_bf, 147456);

  // ---- attention path, chunked over window groups (ws-size adaptive) ----
  int NCA = 1;
  while (NCA < 16 && 4ull * (size_t)(2048 / NCA) * 49 * 192 * 2 > arena_sz)
    NCA <<= 1;
  int Wc = 2048 / NCA;
  size_t Sx = (size_t)Wc * 49 * 192;  // u16 elements per buffer
  for (int cch = 0; cch < NCA; ++cch) {
    int win0 = cch * Wc;
    int tok0 = win0 * 49;
    u16* aout_c = (u16*)arena;
    u16* qb = (u16*)arena + Sx;
    u16* kb = qb + Sx;
    u16* vb = kb + Sx;
    int rows = Wc * 49;
    qkv_fused<<<rows / 64, 256, 0, stream>>>(x, n1w, n1b, qkvw_bf, qkvb,
                                             qb, kb, vb, tok0);
    attn_kernel<<<Wc * 6, 256, 0, stream>>>(qb, kb, vb, rpb, amask, aout_c,
                                            win0);
    proj_fused<<<rows / 64, 256, 0, stream>>>(aout_c, projw_bf, projb, x, out,
                                              tok0);
  }

  // ---- fused MLP: 256 threads, M=128, 2 row-groups/wave, 2 blocks/CU ----
  mlp_fused<<<784, 256, 0, stream>>>(n2w, n2b, fc1w_bf, fc1b, fc2w_bf, fc2b,
                                     out);
}

// Round 7
// 346.627 us; speedup vs baseline: 1.2958x; 1.2958x over previous
//
#include <hip/hip_runtime.h>
#include <hip/hip_bf16.h>

typedef unsigned short u16;
typedef __attribute__((ext_vector_type(8))) short bf16x8;
typedef __attribute__((ext_vector_type(4))) float f32x4;

#define MFMA16(a, b, c) __builtin_amdgcn_mfma_f32_16x16x32_bf16(a, b, c, 0, 0, 0)

__device__ __forceinline__ u16 f2b(float f) {
  union { float f; unsigned u; } x; x.f = f;
  return (u16)((x.u + 0x7fffu + ((x.u >> 16) & 1u)) >> 16);
}

__device__ __forceinline__ void gload_lds16(const void* g, void* l) {
  __builtin_amdgcn_global_load_lds(
      (const __attribute__((address_space(1))) void*)g,
      (__attribute__((address_space(3))) void*)l, 16, 0, 0);
}

// stage 64 rows x 192 cols bf16, chunk(8xbf16) XOR-swizzled by row&7.
// LDS dest linear (wave-uniform base + lane*16), global source pre-swizzled.
__device__ __forceinline__ void stage_64x192(const u16* __restrict__ src,
                                             int stride, u16* dst, int wave,
                                             int lane) {
#pragma unroll
  for (int it = 0; it < 6; ++it) {
    int id = (it * 4 + wave) * 64 + lane;
    int row = id / 24, ph = id - row * 24;
    int lch = (ph & 24) | ((ph ^ (row & 7)) & 7);
    gload_lds16(src + (size_t)row * stride + lch * 8,
                dst + (it * 4 + wave) * 512);
  }
}

// stage 32 rows x 192 cols (fc1 N32 chunk), 3 loads/thread
__device__ __forceinline__ void stage_32x192(const u16* __restrict__ src,
                                             u16* dst, int wave, int lane) {
#pragma unroll
  for (int it = 0; it < 3; ++it) {
    int id = (it * 4 + wave) * 64 + lane;
    int row = id / 24, ph = id - row * 24;
    int lch = (ph & 24) | ((ph ^ (row & 7)) & 7);
    gload_lds16(src + (size_t)row * 192 + lch * 8,
                dst + (it * 4 + wave) * 512);
  }
}

// stage 192 rows x 32 cols (fc2 K32 slice), 4 chunks/row XOR-swizzled by row&3
__device__ __forceinline__ void stage_192x32(const u16* __restrict__ src,
                                             int stride, u16* dst, int wave,
                                             int lane) {
#pragma unroll
  for (int it = 0; it < 3; ++it) {
    int id = (it * 4 + wave) * 64 + lane;
    int row = id >> 2, ph = id & 3;
    int lch = ph ^ (row & 3);
    gload_lds16(src + (size_t)row * stride + lch * 8,
                dst + (it * 4 + wave) * 512);
  }
}

// ---------------- weight f32 -> bf16 ----------------
__global__ __launch_bounds__(256) void cvt_kernel(const float* __restrict__ s,
                                                  u16* __restrict__ d, int n) {
  int i = blockIdx.x * 256 + threadIdx.x;
  if (i < n) d[i] = f2b(s[i]);
}

// ---------------- fused LN1 + shift/window + QKV GEMM ----------------
__global__ __launch_bounds__(256, 2) void qkv_fused(
    const float* __restrict__ x, const float* __restrict__ n1w,
    const float* __restrict__ n1b, const u16* __restrict__ qkvw,
    const float* __restrict__ qkvb_, u16* __restrict__ qb,
    u16* __restrict__ kb, u16* __restrict__ vb, int tok0) {
  __shared__ __align__(16) u16 lds[36864];
  u16* sA = lds;
  u16* sB0 = lds + 12288;
  u16* sB1 = lds + 24576;
  int tid = threadIdx.x, wave = tid >> 6, lane = tid & 63;
  int g = lane >> 4, c = lane & 15, wr = wave * 16;
  int m0 = blockIdx.x * 64;
  // prefetch B chunk 0 while doing LN
  stage_64x192(qkvw, 192, sB0, wave, lane);
  // LN1 over shifted-window source rows (C-layout in regs)
  float vals[12][4];
  int srcrow[4];
#pragma unroll
  for (int reg = 0; reg < 4; ++reg) {
    int rg = tok0 + m0 + wr + 4 * g + reg;
    int win = rg / 49, n = rg - win * 49;
    int bb = win >> 6, wi = win & 63, wh = wi >> 3, ww = wi & 7;
    int rr = n / 7, cc = n - rr * 7;
    int hs = wh * 7 + rr + 3; if (hs >= 56) hs -= 56;
    int ws = ww * 7 + cc + 3; if (ws >= 56) ws -= 56;
    srcrow[reg] = bb * 3136 + hs * 56 + ws;
  }
#pragma unroll
  for (int nt = 0; nt < 12; ++nt)
#pragma unroll
    for (int reg = 0; reg < 4; ++reg)
      vals[nt][reg] = x[(size_t)srcrow[reg] * 192 + nt * 16 + c];
#pragma unroll
  for (int reg = 0; reg < 4; ++reg) {
    float s = 0.f;
#pragma unroll
    for (int nt = 0; nt < 12; ++nt) s += vals[nt][reg];
    s += __shfl_xor(s, 1, 64); s += __shfl_xor(s, 2, 64);
    s += __shfl_xor(s, 4, 64); s += __shfl_xor(s, 8, 64);
    float m = s * (1.f / 192.f), q = 0.f;
#pragma unroll
    for (int nt = 0; nt < 12; ++nt) { float d = vals[nt][reg] - m; q += d * d; }
    q += __shfl_xor(q, 1, 64); q += __shfl_xor(q, 2, 64);
    q += __shfl_xor(q, 4, 64); q += __shfl_xor(q, 8, 64);
    float rs = rsqrtf(q * (1.f / 192.f) + 1e-5f);
#pragma unroll
    for (int nt = 0; nt < 12; ++nt) vals[nt][reg] = (vals[nt][reg] - m) * rs;
  }
#pragma unroll
  for (int nt = 0; nt < 12; ++nt) {
    float wv = n1w[nt * 16 + c], bv = n1b[nt * 16 + c];
#pragma unroll
    for (int reg = 0; reg < 4; ++reg) {
      int r = wr + 4 * g + reg;
      int ch = nt * 2 + (c >> 3);
      int ph = (ch & 24) | ((ch ^ (r & 7)) & 7);
      sA[r * 192 + ph * 8 + (c & 7)] = f2b(vals[nt][reg] * wv + bv);
    }
  }
  __syncthreads();
  bf16x8 afr[6];
  {
    int ar = wr + c;
#pragma unroll
    for (int ks = 0; ks < 6; ++ks) {
      int ch = ks * 4 + g;
      int ph = (ch & 24) | ((ch ^ (ar & 7)) & 7);
      afr[ks] = *(const bf16x8*)(sA + ar * 192 + ph * 8);
    }
  }
  int win0 = tok0 / 49;
  for (int j = 0; j < 9; ++j) {
    u16* nb = (j & 1) ? sB0 : sB1;
    if (j < 8) {
      stage_64x192(qkvw + (size_t)(j + 1) * 64 * 192, 192, nb, wave, lane);
      asm volatile("s_waitcnt vmcnt(6)" ::: "memory");
    } else {
      asm volatile("s_waitcnt vmcnt(0)" ::: "memory");
    }
    __syncthreads();
    const u16* sb = (j & 1) ? sB1 : sB0;
    f32x4 S[4] = {{0,0,0,0},{0,0,0,0},{0,0,0,0},{0,0,0,0}};
#pragma unroll
    for (int ks = 0; ks < 6; ++ks)
#pragma unroll
      for (int nt = 0; nt < 4; ++nt) {
        int br = nt * 16 + c;
        int ch = ks * 4 + g;
        int ph = (ch & 24) | ((ch ^ (br & 7)) & 7);
        bf16x8 bf = *(const bf16x8*)(sb + br * 192 + ph * 8);
        S[nt] = MFMA16(afr[ks], bf, S[nt]);
      }
    int which = j / 3;  // 0=q 1=k 2=v (uniform per chunk)
    u16* dst = which == 0 ? qb : (which == 1 ? kb : vb);
#pragma unroll
    for (int nt = 0; nt < 4; ++nt) {
      int jc = j * 64 + nt * 16 + c;
      int jj = jc - which * 192;
      int hh = jj >> 5, d = jj & 31;
      float bv = qkvb_[jc];
#pragma unroll
      for (int reg = 0; reg < 4; ++reg) {
        int rg = tok0 + m0 + wr + 4 * g + reg;
        int win = rg / 49, n = rg - win * 49;
        dst[((size_t)((win - win0) * 6 + hh) * 49 + n) * 32 + d] =
            f2b(S[nt][reg] + bv);
      }
    }
    __syncthreads();
  }
}

// ---------------- attention: one (window, head) per block ----------------
__global__ __launch_bounds__(256) void attn_kernel(
    const u16* __restrict__ qb, const u16* __restrict__ kb,
    const u16* __restrict__ vb, const float* __restrict__ rpb,
    const float* __restrict__ amask, u16* __restrict__ aout, int win0) {
  __shared__ __align__(16) u16 qs[64 * 32], ks[64 * 32], vst[32 * 64];
  __shared__ __align__(16) float S[64 * 68];
  __shared__ __align__(16) u16 P[64 * 64];
  int tid = threadIdx.x;
  int blk = blockIdx.x;
  int winl = blk / 6, head = blk - winl * 6;
  int wi = (win0 + winl) & 63;
  const size_t base = (size_t)(winl * 6 + head) * 49 * 32;
  {
    int row = tid >> 2, kcl = tid & 3;
    int phys = kcl ^ (row & 3);
    uint4 qv = make_uint4(0, 0, 0, 0), kv = qv, vv = qv;
    if (row < 49) {
      size_t o = base + (size_t)row * 32 + kcl * 8;
      qv = *(const uint4*)(qb + o);
      kv = *(const uint4*)(kb + o);
      vv = *(const uint4*)(vb + o);
    }
    *(uint4*)(qs + row * 32 + phys * 8) = qv;
    *(uint4*)(ks + row * 32 + phys * 8) = kv;
    alignas(16) u16 vu[8];
    *(uint4*)vu = vv;
    int c8 = kcl * 8;
    int kc = row >> 3;
#pragma unroll
    for (int j = 0; j < 8; ++j) {
      int d = c8 + j;
      vst[d * 64 + ((kc ^ (d & 7)) * 8) + (row & 7)] = vu[j];
    }
  }
  __syncthreads();
  int wave = tid >> 6, lane = tid & 63;
  int col = lane & 15, g = lane >> 4;
  {
    int ar = wave * 16 + col;
    bf16x8 af = *(const bf16x8*)(qs + ar * 32 + ((g ^ (ar & 3)) * 8));
    f32x4 zero = {0.f, 0.f, 0.f, 0.f};
#pragma unroll
    for (int nt = 0; nt < 4; ++nt) {
      int br = nt * 16 + col;
      bf16x8 bfr = *(const bf16x8*)(ks + br * 32 + ((g ^ (br & 3)) * 8));
      f32x4 sacc = MFMA16(af, bfr, zero);
#pragma unroll
      for (int reg = 0; reg < 4; ++reg)
        S[(wave * 16 + 4 * g + reg) * 68 + nt * 16 + col] = sacc[reg];
    }
  }
  __syncthreads();
  {
    int r = tid >> 2, p = tid & 3;
    int rb = (r < 49) ? r : 0;
    int i1 = rb / 7, j1 = rb - i1 * 7;
    const float scale = 0.17677669529663687f;
    const float* Srow = S + r * 68;
    float vals[16];
    float mx = -1e30f;
#pragma unroll
    for (int t = 0; t < 16; ++t) {
      int cc = p * 16 + t;
      float v = -1e30f;
      if (cc < 49) {
        int i2 = cc / 7, j2 = cc - i2 * 7;
        int ridx = (i1 - i2 + 6) * 13 + (j1 - j2 + 6);
        v = Srow[cc] * scale + rpb[ridx * 6 + head] +
            amask[(size_t)wi * 2401 + rb * 49 + cc];
      }
      vals[t] = v;
      mx = fmaxf(mx, v);
    }
    mx = fmaxf(mx, __shfl_xor(mx, 1, 64));
    mx = fmaxf(mx, __shfl_xor(mx, 2, 64));
    float se = 0.f;
#pragma unroll
    for (int t = 0; t < 16; ++t) {
      float e = __expf(vals[t] - mx);
      vals[t] = e;
      se += e;
    }
    se += __shfl_xor(se, 1, 64);
    se += __shfl_xor(se, 2, 64);
    float inv = 1.0f / se;
#pragma unroll
    for (int t = 0; t < 16; ++t) {
      int cc = p * 16 + t;
      P[r * 64 + (((cc >> 3) ^ (r & 7)) * 8) + (cc & 7)] = f2b(vals[t] * inv);
    }
  }
  __syncthreads();
  {
    f32x4 oacc[2] = {{0,0,0,0},{0,0,0,0}};
    int ar = wave * 16 + col;
#pragma unroll
    for (int kt = 0; kt < 2; ++kt) {
      bf16x8 pf = *(const bf16x8*)(P + ar * 64 + (((kt * 4 + g) ^ (ar & 7)) * 8));
#pragma unroll
      for (int nt = 0; nt < 2; ++nt) {
        int d = nt * 16 + col;
        bf16x8 vf = *(const bf16x8*)(vst + d * 64 + (((kt * 4 + g) ^ (d & 7)) * 8));
        oacc[nt] = MFMA16(pf, vf, oacc[nt]);
      }
    }
#pragma unroll
    for (int nt = 0; nt < 2; ++nt)
#pragma unroll
      for (int reg = 0; reg < 4; ++reg) {
        int rloc = wave * 16 + 4 * g + reg;
        if (rloc < 49)
          aout[((size_t)winl * 49 + rloc) * 192 + head * 32 + nt * 16 + col] =
              f2b(oacc[nt][reg]);
      }
  }
}

// ---------------- fused proj GEMM + window reverse + unshift + residual ----------------
__global__ __launch_bounds__(256, 2) void proj_fused(
    const u16* __restrict__ aout, const u16* __restrict__ projw,
    const float* __restrict__ pb, const float* __restrict__ x,
    float* __restrict__ out, int tok0) {
  __shared__ __align__(16) u16 lds[36864];
  u16* sA = lds;
  u16* sB0 = lds + 12288;
  u16* sB1 = lds + 24576;
  int tid = threadIdx.x, wave = tid >> 6, lane = tid & 63;
  int g = lane >> 4, c = lane & 15, wr = wave * 16;
  int m0 = blockIdx.x * 64;
  stage_64x192(aout + (size_t)m0 * 192, 192, sA, wave, lane);
  stage_64x192(projw, 192, sB0, wave, lane);
  asm volatile("s_waitcnt vmcnt(0)" ::: "memory");
  __syncthreads();
  bf16x8 afr[6];
  {
    int ar = wr + c;
#pragma unroll
    for (int ks = 0; ks < 6; ++ks) {
      int ch = ks * 4 + g;
      int ph = (ch & 24) | ((ch ^ (ar & 7)) & 7);
      afr[ks] = *(const bf16x8*)(sA + ar * 192 + ph * 8);
    }
  }
  // row -> output token mapping (window reverse + unshift)
  size_t trow[4];
#pragma unroll
  for (int reg = 0; reg < 4; ++reg) {
    int rg = tok0 + m0 + wr + 4 * g + reg;
    int win = rg / 49, n = rg - win * 49;
    int b_ = win >> 6, wi = win & 63;
    int wh = wi >> 3, ww = wi & 7;
    int rr = n / 7, cc = n - rr * 7;
    int hd_ = wh * 7 + rr + 3; if (hd_ >= 56) hd_ -= 56;
    int wd = ww * 7 + cc + 3; if (wd >= 56) wd -= 56;
    trow[reg] = (size_t)b_ * 3136 + hd_ * 56 + wd;
  }
  for (int j = 0; j < 3; ++j) {
    if (j < 2) {
      u16* nb = (j & 1) ? sB0 : sB1;
      stage_64x192(projw + (size_t)(j + 1) * 64 * 192, 192, nb, wave, lane);
      asm volatile("s_waitcnt vmcnt(6)" ::: "memory");
    } else {
      asm volatile("s_waitcnt vmcnt(0)" ::: "memory");
    }
    __syncthreads();
    const u16* sb = (j & 1) ? sB1 : sB0;
    f32x4 S[4] = {{0,0,0,0},{0,0,0,0},{0,0,0,0},{0,0,0,0}};
#pragma unroll
    for (int ks = 0; ks < 6; ++ks)
#pragma unroll
      for (int nt = 0; nt < 4; ++nt) {
        int br = nt * 16 + c;
        int ch = ks * 4 + g;
        int ph = (ch & 24) | ((ch ^ (br & 7)) & 7);
        bf16x8 bf = *(const bf16x8*)(sb + br * 192 + ph * 8);
        S[nt] = MFMA16(afr[ks], bf, S[nt]);
      }
#pragma unroll
    for (int nt = 0; nt < 4; ++nt) {
      int jc = j * 64 + nt * 16 + c;
      float bv = pb[jc];
#pragma unroll
      for (int reg = 0; reg < 4; ++reg) {
        size_t o = trow[reg] * 192 + jc;
        out[o] = x[o] + S[nt][reg] + bv;
      }
    }
    __syncthreads();
  }
}

// ---------------- fused LN2 + fc1 + GELU + fc2 + residual ----------------
// 256 thr / 4 waves, M=64, N-chunk=32 (24 phases), double-buffered weights.
// LDS 52KB + VGPR<=170 -> 3 blocks/CU; split staging overlaps fc1 and PV.
__global__ __launch_bounds__(256, 3) void mlp_fused(
    const float* __restrict__ n2w, const float* __restrict__ n2b,
    const u16* __restrict__ w1, const float* __restrict__ b1,
    const u16* __restrict__ w2, const float* __restrict__ b2,
    float* __restrict__ out) {
  __shared__ __align__(16) u16 lds[26624];  // 52 KB
  u16* c10 = lds;            // 32x192 fc1 chunk, buf 0
  u16* c11 = lds + 6144;     // buf 1
  u16* c20 = lds + 12288;    // 192x32 fc2 slice, buf 0
  u16* c21 = lds + 18432;    // buf 1
  u16* sP  = lds + 24576;    // 64x32 P tile
  u16* sA  = lds;            // 64x192 overlay (c10+c11), dead after afr loads
  int tid = threadIdx.x, wave = tid >> 6, lane = tid & 63;
  int g = lane >> 4, c = lane & 15, wr = wave * 16;
  int m0 = blockIdx.x * 64;
  // ---- LN2 -> sA (bf16, swizzled) ----
  {
    float v[12][4];
    int rr[4];
#pragma unroll
    for (int reg = 0; reg < 4; ++reg) rr[reg] = m0 + wr + 4 * g + reg;
#pragma unroll
    for (int nt = 0; nt < 12; ++nt)
#pragma unroll
      for (int reg = 0; reg < 4; ++reg)
        v[nt][reg] = out[(size_t)rr[reg] * 192 + nt * 16 + c];
#pragma unroll
    for (int reg = 0; reg < 4; ++reg) {
      float s = 0.f;
#pragma unroll
      for (int nt = 0; nt < 12; ++nt) s += v[nt][reg];
      s += __shfl_xor(s, 1, 64); s += __shfl_xor(s, 2, 64);
      s += __shfl_xor(s, 4, 64); s += __shfl_xor(s, 8, 64);
      float m = s * (1.f / 192.f), q = 0.f;
#pragma unroll
      for (int nt = 0; nt < 12; ++nt) { float d = v[nt][reg] - m; q += d * d; }
      q += __shfl_xor(q, 1, 64); q += __shfl_xor(q, 2, 64);
      q += __shfl_xor(q, 4, 64); q += __shfl_xor(q, 8, 64);
      float rs = rsqrtf(q * (1.f / 192.f) + 1e-5f);
#pragma unroll
      for (int nt = 0; nt < 12; ++nt) v[nt][reg] = (v[nt][reg] - m) * rs;
    }
#pragma unroll
    for (int nt = 0; nt < 12; ++nt) {
      float wv = n2w[nt * 16 + c], bv = n2b[nt * 16 + c];
#pragma unroll
      for (int reg = 0; reg < 4; ++reg) {
        int r = wr + 4 * g + reg;
        int ch = nt * 2 + (c >> 3);
        int ph = (ch & 24) | ((ch ^ (r & 7)) & 7);
        sA[r * 192 + ph * 8 + (c & 7)] = f2b(v[nt][reg] * wv + bv);
      }
    }
  }
  __syncthreads();  // sA visible
  bf16x8 afr[6];
  {
    int ar = wr + c;
#pragma unroll
    for (int ks = 0; ks < 6; ++ks) {
      int ch = ks * 4 + g;
      int ph = (ch & 24) | ((ch ^ (ar & 7)) & 7);
      afr[ks] = *(const bf16x8*)(sA + ar * 192 + ph * 8);
    }
  }
  __syncthreads();  // all afr reads done -> sA region (c10,c11) reusable
  // prologue: stage chunk 0 into buf 0
  stage_32x192(w1, c10, wave, lane);
  stage_192x32(w2, 768, c20, wave, lane);
  f32x4 o[12];
#pragma unroll
  for (int i = 0; i < 12; ++i) o[i] = (f32x4){0.f, 0.f, 0.f, 0.f};
  __syncthreads();  // drains prologue stage; buf0 ready
  for (int j = 0; j < 24; ++j) {
    int cur = j & 1;
    const u16* r1 = cur ? c11 : c10;
    const u16* r2 = cur ? c21 : c20;
    // stage fc1 chunk j+1 -> other buffer (overlaps fc1+GELU; drained at mid barrier)
    if (j < 23)
      stage_32x192(w1 + (size_t)(j + 1) * 32 * 192, cur ? c10 : c11, wave, lane);
    // ---- fc1: S = A @ w1_chunk^T ----
    f32x4 S[2] = {{0,0,0,0},{0,0,0,0}};
#pragma unroll
    for (int ks = 0; ks < 6; ++ks)
#pragma unroll
      for (int nt = 0; nt < 2; ++nt) {
        int br = nt * 16 + c;
        int ch = ks * 4 + g;
        int ph = (ch & 24) | ((ch ^ (br & 7)) & 7);
        bf16x8 bf = *(const bf16x8*)(r1 + br * 192 + ph * 8);
        S[nt] = MFMA16(afr[ks], bf, S[nt]);
      }
    // ---- fast GELU -> sP ----
#pragma unroll
    for (int nt = 0; nt < 2; ++nt) {
      float bv = b1[j * 32 + nt * 16 + c];
      int col = nt * 16 + c;
#pragma unroll
      for (int reg = 0; reg < 4; ++reg) {
        int r = wr + 4 * g + reg;
        float vv = S[nt][reg] + bv;
        float u2 = vv * (1.5957691216f + 0.0713548163f * vv * vv);
        float gl = vv / (1.f + __expf(-u2));
        int ph = (col >> 3) ^ (r & 3);
        sP[r * 32 + ph * 8 + (col & 7)] = f2b(gl);
      }
    }
    __syncthreads();  // sP visible; r1 reads done; fc1(j+1) stage drained
    // stage fc2 slice j+1 (overlaps PV; drained at end barrier)
    if (j < 23)
      stage_192x32(w2 + (size_t)(j + 1) * 32, 768, cur ? c20 : c21, wave, lane);
    // ---- PV: o += P @ w2_slice ----
    {
      int pr = wr + c;
      bf16x8 pf = *(const bf16x8*)(sP + pr * 32 + ((g ^ (pr & 3)) * 8));
#pragma unroll
      for (int nt = 0; nt < 12; ++nt) {
        int c2 = nt * 16 + c;
        bf16x8 bf = *(const bf16x8*)(r2 + c2 * 32 + ((g ^ (c2 & 3)) * 8));
        o[nt] = MFMA16(pf, bf, o[nt]);
      }
    }
    __syncthreads();  // r2 + sP reads done; fc2(j+1) stage drained
  }
  // epilogue: residual (re-read) + bias
#pragma unroll
  for (int nt = 0; nt < 12; ++nt) {
    float bv = b2[nt * 16 + c];
#pragma unroll
    for (int reg = 0; reg < 4; ++reg) {
      size_t oo = (size_t)(m0 + wr + 4 * g + reg) * 192 + nt * 16 + c;
      out[oo] = out[oo] + o[nt][reg] + bv;
    }
  }
}

extern "C" void kernel_launch(void* const* d_in, const int* in_sizes, int n_in,
                              void* d_out, int out_size, void* d_ws, size_t ws_size,
                              hipStream_t stream) {
  (void)in_sizes; (void)n_in; (void)out_size;
  const float* x     = (const float*)d_in[0];
  const float* amask = (const float*)d_in[1];
  const float* n1w   = (const float*)d_in[2];
  const float* n1b   = (const float*)d_in[3];
  const float* qkvw  = (const float*)d_in[4];
  const float* qkvb  = (const float*)d_in[5];
  const float* rpb   = (const float*)d_in[6];
  const float* projw = (const float*)d_in[7];
  const float* projb = (const float*)d_in[8];
  const float* n2w   = (const float*)d_in[9];
  const float* n2b   = (const float*)d_in[10];
  const float* fc1w  = (const float*)d_in[11];
  const float* fc1b  = (const float*)d_in[12];
  const float* fc2w  = (const float*)d_in[13];
  const float* fc2b  = (const float*)d_in[14];
  float* out = (float*)d_out;
  char* ws = (char*)d_ws;

  u16* qkvw_bf = (u16*)(ws);
  u16* projw_bf = (u16*)(ws + 221184);
  u16* fc1w_bf = (u16*)(ws + 221184 + 73728);
  u16* fc2w_bf = (u16*)(ws + 221184 + 73728 + 294912);
  char* arena = ws + (1 << 20);
  size_t arena_sz = ws_size > (1 << 20) ? ws_size - (1 << 20) : 0;

  cvt_kernel<<<(110592 + 255) / 256, 256, 0, stream>>>(qkvw, qkvw_bf, 110592);
  cvt_kernel<<<(36864 + 255) / 256, 256, 0, stream>>>(projw, projw_bf, 36864);
  cvt_kernel<<<(147456 + 255) / 256, 256, 0, stream>>>(fc1w, fc1w_bf, 147456);
  cvt_kernel<<<(147456 + 255) / 256, 256, 0, stream>>>(fc2w, fc2w_bf, 147456);

  // ---- attention path, chunked over window groups (ws-size adaptive) ----
  int NCA = 1;
  while (NCA < 16 && 4ull * (size_t)(2048 / NCA) * 49 * 192 * 2 > arena_sz)
    NCA <<= 1;
  int Wc = 2048 / NCA;
  size_t Sx = (size_t)Wc * 49 * 192;  // u16 elements per buffer
  for (int cch = 0; cch < NCA; ++cch) {
    int win0 = cch * Wc;
    int tok0 = win0 * 49;
    u16* aout_c = (u16*)arena;
    u16* qb = (u16*)arena + Sx;
    u16* kb = qb + Sx;
    u16* vb = kb + Sx;
    int rows = Wc * 49;
    qkv_fused<<<rows / 64, 256, 0, stream>>>(x, n1w, n1b, qkvw_bf, qkvb,
                                             qb, kb, vb, tok0);
    attn_kernel<<<Wc * 6, 256, 0, stream>>>(qb, kb, vb, rpb, amask, aout_c,
                                            win0);
    proj_fused<<<rows / 64, 256, 0, stream>>>(aout_c, projw_bf, projb, x, out,
                                              tok0);
  }

  // ---- fused MLP: M=64, N-chunk=32, double-buffered, 3 blocks/CU ----
  mlp_fused<<<1568, 256, 0, stream>>>(n2w, n2b, fc1w_bf, fc1b, fc2w_bf, fc2b,
                                      out);
}